// Round 14
// baseline (156.982 us; speedup 1.0000x reference)
//
#include <hip/hip_runtime.h>
#include <hip/hip_bf16.h>
#include <cstdint>
#include <cstddef>

#define HEADS 12
#define HD    64
#define NB    4
#define SEQ   2048
#define DIM   768
#define NQKV  2304

// Q pre-scale: (1/sqrt(HEADS)) * log2(e)  -> scores arrive in exp2 domain
static constexpr float QSCALE = 0.2886751345948129f * 1.4426950408889634f;

typedef __attribute__((ext_vector_type(8))) short short8;
typedef __attribute__((ext_vector_type(4))) short short4v;
typedef __attribute__((ext_vector_type(4))) float f32x4;

__device__ inline unsigned short f2bf(float x) {          // RNE, for cold paths
    union { float f; uint32_t u; } v; v.f = x;
    return (unsigned short)((v.u + 0x7fffu + ((v.u >> 16) & 1u)) >> 16);
}

__device__ inline unsigned short f2bf_fast(float x) {     // compiler hw-convert
    __hip_bfloat16 h = __float2bfloat16(x);
    unsigned short u;
    __builtin_memcpy(&u, &h, 2);
    return u;
}

__device__ inline void gld16(const void* g, void* l) {
    __builtin_amdgcn_global_load_lds(
        (const __attribute__((address_space(1))) unsigned int*)g,
        (__attribute__((address_space(3))) unsigned int*)l, 16, 0, 0);
}

// ---------------------------------------------------------------------------
// Fused prep kernel: x->bf16 convert + both weight transpose-converts.
// ---------------------------------------------------------------------------
__device__ inline void transpose_tile(
    const float* __restrict__ w, unsigned short* __restrict__ wT,
    int ncols, int nrows, int bx, int by, float (*tile)[65])
{
    const int k0 = by * 64;
    const int n0 = bx * 64;
    const int tr = threadIdx.x >> 4;
    const int tc4 = (threadIdx.x & 15) * 4;
    #pragma unroll
    for (int it = 0; it < 4; ++it) {
        const int kk = tr + it * 16;
        *reinterpret_cast<float4*>(&tile[kk][tc4]) =
            *reinterpret_cast<const float4*>(w + (size_t)(k0 + kk) * ncols + n0 + tc4);
    }
    __syncthreads();
    #pragma unroll
    for (int it = 0; it < 4; ++it) {
        const int nn = tr + it * 16;
        short4v o;
        #pragma unroll
        for (int r = 0; r < 4; ++r) o[r] = (short)f2bf(tile[tc4 + r][nn]);
        *reinterpret_cast<short4v*>(wT + (size_t)(n0 + nn) * nrows + k0 + tc4) = o;
    }
}

__global__ __launch_bounds__(256) void prep_kernel(
    const float* __restrict__ x, unsigned short* __restrict__ xb,
    const float* __restrict__ wq, unsigned short* __restrict__ wqT,
    const float* __restrict__ wo, unsigned short* __restrict__ woT)
{
    __shared__ float tile[64][65];
    const int bid = blockIdx.x;
    if (bid < 3072) {
        const size_t i = ((size_t)bid * 256 + threadIdx.x) * 8;
        const float4 a = *reinterpret_cast<const float4*>(x + i);
        const float4 b = *reinterpret_cast<const float4*>(x + i + 4);
        short8 o;
        o[0] = (short)f2bf(a.x); o[1] = (short)f2bf(a.y);
        o[2] = (short)f2bf(a.z); o[3] = (short)f2bf(a.w);
        o[4] = (short)f2bf(b.x); o[5] = (short)f2bf(b.y);
        o[6] = (short)f2bf(b.z); o[7] = (short)f2bf(b.w);
        *reinterpret_cast<short8*>(xb + i) = o;
    } else if (bid < 3072 + 432) {
        const int r = bid - 3072;
        transpose_tile(wq, wqT, NQKV, DIM, r % 36, r / 36, tile);
    } else {
        const int r = bid - 3504;
        transpose_tile(wo, woT, DIM, DIM, r % 12, r / 12, tile);
    }
}

// ---------------------------------------------------------------------------
// Kernel 1: QKV GEMM, bf16 MFMA, T3-minimal 2-phase (R10 form, proven).
// ---------------------------------------------------------------------------
__global__ __launch_bounds__(512) void qkv_gemm_bf16(
    const unsigned short* __restrict__ A,   // [8192][768]
    const unsigned short* __restrict__ BT,  // [2304][768]
    const float* __restrict__ bias,
    unsigned short* __restrict__ qb, unsigned short* __restrict__ kb,
    unsigned short* __restrict__ vt)
{
    __shared__ __align__(16) unsigned short As[2][128][64];
    __shared__ __align__(16) unsigned short Bs[2][128][64];

    const int tid = threadIdx.x;
    const int wave = tid >> 6;        // 0..7
    const int lane = tid & 63;
    const int col = lane & 15;
    const int g = lane >> 4;
    const int m0 = blockIdx.y * 128;
    const int n0 = blockIdx.x * 128;
    const int wr = wave >> 2;         // 0..1  row half (64 rows)
    const int wc = wave & 3;          // 0..3  col quarter (32 cols)

    f32x4 acc[4][2] = {};

    auto STAGE = [&](int kt, int bsel) {
        #pragma unroll
        for (int it = 0; it < 2; ++it) {
            const int slot = tid + it * 512;
            const int row = slot >> 3;
            const int cg = (slot & 7) ^ (row & 7);
            gld16(A + (size_t)(m0 + row) * DIM + kt + cg * 8,
                  &As[bsel][0][0] + (size_t)slot * 8);
            gld16(BT + (size_t)(n0 + row) * DIM + kt + cg * 8,
                  &Bs[bsel][0][0] + (size_t)slot * 8);
        }
    };

    const int NKT = DIM / 64;   // 12
    STAGE(0, 0);
    asm volatile("s_waitcnt vmcnt(0)" ::: "memory");
    __builtin_amdgcn_s_barrier();

    for (int t = 0; t < NKT; ++t) {
        const int cur = t & 1;
        if (t + 1 < NKT) STAGE((t + 1) * 64, cur ^ 1);  // overlap with compute

        #pragma unroll
        for (int ks = 0; ks < 2; ++ks) {
            short8 af[4], bf[2];
            #pragma unroll
            for (int i = 0; i < 4; ++i) {
                const int ra = wr * 64 + i * 16 + col;
                af[i] = *reinterpret_cast<const short8*>(
                    &As[cur][ra][(((ks * 4 + g) ^ (ra & 7)) << 3)]);
            }
            #pragma unroll
            for (int j = 0; j < 2; ++j) {
                const int rb = wc * 32 + j * 16 + col;
                bf[j] = *reinterpret_cast<const short8*>(
                    &Bs[cur][rb][(((ks * 4 + g) ^ (rb & 7)) << 3)]);
            }
            #pragma unroll
            for (int i = 0; i < 4; ++i)
                #pragma unroll
                for (int j = 0; j < 2; ++j)
                    acc[i][j] = __builtin_amdgcn_mfma_f32_16x16x32_bf16(
                        af[i], bf[j], acc[i][j], 0, 0, 0);
        }

        if (t + 1 < NKT) {
            asm volatile("s_waitcnt vmcnt(0)" ::: "memory");  // t+1 tile landed
            __builtin_amdgcn_s_barrier();  // + all waves done reading buf[cur]
        }
    }

    // Epilogue: bias + bf16 scatter. which is block-uniform (768 % 128 == 0).
    const int which = n0 / DIM;
    #pragma unroll
    for (int j = 0; j < 2; ++j) {
        const int n = n0 + wc * 32 + j * 16 + col;
        const int rem = n - which * DIM;
        const int h = rem >> 6, dh = rem & 63;
        const float bj = bias[n];
        #pragma unroll
        for (int i = 0; i < 4; ++i) {
            const int mbase = m0 + wr * 64 + i * 16 + g * 4;
            const int b_ = mbase >> 11;
            const int s_ = mbase & 2047;
            const size_t bh = (size_t)(b_ * HEADS + h);
            if (which == 2) {
                short4v pk;
                #pragma unroll
                for (int r = 0; r < 4; ++r)
                    pk[r] = (short)f2bf(acc[i][j][r] + bj);
                *reinterpret_cast<short4v*>(vt + (bh * HD + dh) * SEQ + s_) = pk;
            } else {
                unsigned short* dst = (which == 0) ? qb : kb;
                const float sc = (which == 0) ? QSCALE : 1.0f;
                #pragma unroll
                for (int r = 0; r < 4; ++r)
                    dst[(bh * SEQ + s_ + r) * HD + dh] =
                        f2bf((acc[i][j][r] + bj) * sc);
            }
        }
    }
}

// ---------------------------------------------------------------------------
// Kernel 2: flash attention — T15 double-pipeline.
// Per iter t: [vmcnt(0); ONE barrier; STAGE(t+1)] then QK(t) (MFMA) emitted
// back-to-back with SM(t-1) (VALU) — independent, compiler interleaves —
// then PV(t-1). K double-buffered; V TRIPLE-buffered so PV(t-1) never
// collides with STAGE(t+1). Scores double-state stp/stn (static idx).
// ones-MFMA row-sum kept; setprio only around PV (so it can't fence QK||SM).
// ---------------------------------------------------------------------------
__global__ __launch_bounds__(512) void attn_kernel(
    const unsigned short* __restrict__ qb, const unsigned short* __restrict__ kbuf,
    const unsigned short* __restrict__ vt, unsigned short* __restrict__ ctxb)
{
    __shared__ __align__(16) unsigned short Ks[2][64][64];  // [buf][key][hd]
    __shared__ __align__(16) unsigned short Vs[3][64][64];  // [buf][hd][key]
    __shared__ __align__(16) unsigned short Ps[8][16][64];  // wave-private

    const int tid = threadIdx.x;
    const int wave = tid >> 6;
    const int lane = tid & 63;
    const int col = lane & 15;
    const int g   = lane >> 4;

    // XCD swizzle: grid = 768 blocks = 8 XCDs x 96; XCD i gets bh in [i*6,i*6+6)
    const int bid = blockIdx.x;
    const int vbid = (bid & 7) * 96 + (bid >> 3);
    const int bh = vbid >> 4;          // 0..47
    const int q0 = (vbid & 15) * 128;  // q-tile
    const int wq = q0 + wave * 16 + col;

    const size_t hb = (size_t)bh * SEQ * HD;

    short8 qf[2];
    {
        const unsigned short* src = qb + hb + (size_t)wq * HD + g * 8;
        qf[0] = *reinterpret_cast<const short8*>(src);
        qf[1] = *reinterpret_cast<const short8*>(src + 32);
    }

    const short ONE = (short)0x3F80;
    const short8 ONES = {ONE, ONE, ONE, ONE, ONE, ONE, ONE, ONE};

    f32x4 acc4[4] = {};
    f32x4 acc5 = {};          // running row-sum of P

    const unsigned short* Kg = kbuf + hb;
    const unsigned short* Vg = vt + hb;

    const int srow = tid >> 3;       // 0..63
    const int scl  = tid & 7;
    const int scg  = scl ^ (srow & 7);

    auto STAGE = [&](int jt, int kbsel, int vbsel) {
        const int kb0 = jt * 64;
        gld16(Kg + (size_t)(kb0 + srow) * HD + scg * 8,
              &Ks[kbsel][0][0] + (size_t)tid * 8);
        gld16(Vg + (size_t)srow * SEQ + kb0 + scg * 8,
              &Vs[vbsel][0][0] + (size_t)tid * 8);
    };

    const int NT = SEQ / 64;   // 32

    // prologue: tile 0 staged+synced; tile 1 in flight; scores(0) computed.
    STAGE(0, 0, 0);
    asm volatile("s_waitcnt vmcnt(0)" ::: "memory");
    __builtin_amdgcn_s_barrier();
    STAGE(1, 1, 1);

    f32x4 stp[4] = {};
    #pragma unroll
    for (int m = 0; m < 4; ++m) {
        const int row = m * 16 + col;
        const short8 kf0 = *reinterpret_cast<const short8*>(
            &Ks[0][row][((g ^ (row & 7)) << 3)]);
        const short8 kf1 = *reinterpret_cast<const short8*>(
            &Ks[0][row][(((g + 4) ^ (row & 7)) << 3)]);
        stp[m] = __builtin_amdgcn_mfma_f32_16x16x32_bf16(kf0, qf[0], stp[m], 0, 0, 0);
        stp[m] = __builtin_amdgcn_mfma_f32_16x16x32_bf16(kf1, qf[1], stp[m], 0, 0, 0);
    }

    int vm1 = 0, vcur = 1, vnxt = 2;   // (t-1)%3, t%3, (t+1)%3 for t=1

    for (int t = 1; t < NT; ++t) {
        const int kcur = t & 1;
        asm volatile("s_waitcnt vmcnt(0)" ::: "memory");  // STAGE(t) landed
        __builtin_amdgcn_s_barrier();   // tile t visible; all t-1 readers done
        if (t + 1 < NT) STAGE(t + 1, kcur ^ 1, vnxt);

        // QK(t)  (MFMA)  — independent of SM(t-1) below; compiler interleaves
        f32x4 stn[4] = {};
        #pragma unroll
        for (int m = 0; m < 4; ++m) {
            const int row = m * 16 + col;
            const short8 kf0 = *reinterpret_cast<const short8*>(
                &Ks[kcur][row][((g ^ (row & 7)) << 3)]);
            const short8 kf1 = *reinterpret_cast<const short8*>(
                &Ks[kcur][row][(((g + 4) ^ (row & 7)) << 3)]);
            stn[m] = __builtin_amdgcn_mfma_f32_16x16x32_bf16(kf0, qf[0], stn[m], 0, 0, 0);
            stn[m] = __builtin_amdgcn_mfma_f32_16x16x32_bf16(kf1, qf[1], stn[m], 0, 0, 0);
        }

        // SM(t-1)  (VALU): p = exp2(stp); pack bf16 -> Ps (wave-private)
        #pragma unroll
        for (int m = 0; m < 4; ++m) {
            float p[4];
            p[0] = __builtin_amdgcn_exp2f(stp[m][0]);
            p[1] = __builtin_amdgcn_exp2f(stp[m][1]);
            p[2] = __builtin_amdgcn_exp2f(stp[m][2]);
            p[3] = __builtin_amdgcn_exp2f(stp[m][3]);
            short4v pk;
            #pragma unroll
            for (int r = 0; r < 4; ++r) pk[r] = (short)f2bf_fast(p[r]);
            const int scw = (2 * m + (g >> 1)) ^ (col & 7);
            *reinterpret_cast<short4v*>(
                &Ps[wave][col][(scw << 3) + ((g & 1) << 2)]) = pk;
        }
        const short8 pf0 = *reinterpret_cast<const short8*>(
            &Ps[wave][col][((g ^ (col & 7)) << 3)]);
        const short8 pf1 = *reinterpret_cast<const short8*>(
            &Ps[wave][col][(((g + 4) ^ (col & 7)) << 3)]);

        // PV(t-1): acc += P(t-1) @ V(t-1); row-sum via ones-MFMA
        __builtin_amdgcn_s_setprio(1);
        #pragma unroll
        for (int nb = 0; nb < 4; ++nb) {
            const int row = nb * 16 + col;
            const short8 vf0 = *reinterpret_cast<const short8*>(
                &Vs[vm1][row][((g ^ (row & 7)) << 3)]);
            const short8 vf1 = *reinterpret_cast<const short8*>(
                &Vs[vm1][row][(((g + 4) ^ (row & 7)) << 3)]);
            acc4[nb] = __builtin_amdgcn_mfma_f32_16x16x32_bf16(pf0, vf0, acc4[nb], 0, 0, 0);
            acc4[nb] = __builtin_amdgcn_mfma_f32_16x16x32_bf16(pf1, vf1, acc4[nb], 0, 0, 0);
        }
        acc5 = __builtin_amdgcn_mfma_f32_16x16x32_bf16(pf0, ONES, acc5, 0, 0, 0);
        acc5 = __builtin_amdgcn_mfma_f32_16x16x32_bf16(pf1, ONES, acc5, 0, 0, 0);
        __builtin_amdgcn_s_setprio(0);

        // rotate pipeline state
        #pragma unroll
        for (int m = 0; m < 4; ++m) stp[m] = stn[m];
        vm1 = vcur; vcur = vnxt; vnxt = (vnxt + 1 == 3) ? 0 : vnxt + 1;
    }

    // epilogue: SM(NT-1) + PV(NT-1)  (vm1 == (NT-1)%3 after final rotation)
    {
        #pragma unroll
        for (int m = 0; m < 4; ++m) {
            float p[4];
            p[0] = __builtin_amdgcn_exp2f(stp[m][0]);
            p[1] = __builtin_amdgcn_exp2f(stp[m][1]);
            p[2] = __builtin_amdgcn_exp2f(stp[m][2]);
            p[3] = __builtin_amdgcn_exp2f(stp[m][3]);
            short4v pk;
            #pragma unroll
            for (int r = 0; r < 4; ++r) pk[r] = (short)f2bf_fast(p[r]);
            const int scw = (2 * m + (g >> 1)) ^ (col & 7);
            *reinterpret_cast<short4v*>(
                &Ps[wave][col][(scw << 3) + ((g & 1) << 2)]) = pk;
        }
        const short8 pf0 = *reinterpret_cast<const short8*>(
            &Ps[wave][col][((g ^ (col & 7)) << 3)]);
        const short8 pf1 = *reinterpret_cast<const short8*>(
            &Ps[wave][col][(((g + 4) ^ (col & 7)) << 3)]);
        #pragma unroll
        for (int nb = 0; nb < 4; ++nb) {
            const int row = nb * 16 + col;
            const short8 vf0 = *reinterpret_cast<const short8*>(
                &Vs[vm1][row][((g ^ (row & 7)) << 3)]);
            const short8 vf1 = *reinterpret_cast<const short8*>(
                &Vs[vm1][row][(((g + 4) ^ (row & 7)) << 3)]);
            acc4[nb] = __builtin_amdgcn_mfma_f32_16x16x32_bf16(pf0, vf0, acc4[nb], 0, 0, 0);
            acc4[nb] = __builtin_amdgcn_mfma_f32_16x16x32_bf16(pf1, vf1, acc4[nb], 0, 0, 0);
        }
        acc5 = __builtin_amdgcn_mfma_f32_16x16x32_bf16(pf0, ONES, acc5, 0, 0, 0);
        acc5 = __builtin_amdgcn_mfma_f32_16x16x32_bf16(pf1, ONES, acc5, 0, 0, 0);
    }

    // normalize by acc5 (lane-local row sums), write bf16 ctx
    float lr[4];
    #pragma unroll
    for (int r = 0; r < 4; ++r) lr[r] = 1.0f / acc5[r];
    const int b_ = bh / HEADS;
    const int h = bh - b_ * HEADS;
    #pragma unroll
    for (int nb = 0; nb < 4; ++nb)
        #pragma unroll
        for (int r = 0; r < 4; ++r) {
            const int s_ = q0 + wave * 16 + g * 4 + r;
            ctxb[((size_t)b_ * SEQ + s_) * DIM + h * HD + nb * 16 + col] =
                f2bf_fast(acc4[nb][r] * lr[r]);
        }
}

// ---------------------------------------------------------------------------
// Kernel 3: output projection, bf16 MFMA, T3-minimal 2-phase (R10 form).
// ---------------------------------------------------------------------------
__global__ __launch_bounds__(512) void out_gemm_bf16(
    const unsigned short* __restrict__ A,   // ctxb [8192][768]
    const unsigned short* __restrict__ BT,  // woT  [768][768]
    const float* __restrict__ bias, float* __restrict__ out)
{
    __shared__ __align__(16) unsigned short As[2][128][64];
    __shared__ __align__(16) unsigned short Bs[2][128][64];

    const int tid = threadIdx.x;
    const int wave = tid >> 6;
    const int lane = tid & 63;
    const int col = lane & 15;
    const int g = lane >> 4;
    const int m0 = blockIdx.y * 128;
    const int n0 = blockIdx.x * 128;
    const int wr = wave >> 2;
    const int wc = wave & 3;

    f32x4 acc[4][2] = {};

    auto STAGE = [&](int kt, int bsel) {
        #pragma unroll
        for (int it = 0; it < 2; ++it) {
            const int slot = tid + it * 512;
            const int row = slot >> 3;
            const int cg = (slot & 7) ^ (row & 7);
            gld16(A + (size_t)(m0 + row) * DIM + kt + cg * 8,
                  &As[bsel][0][0] + (size_t)slot * 8);
            gld16(BT + (size_t)(n0 + row) * DIM + kt + cg * 8,
                  &Bs[bsel][0][0] + (size_t)slot * 8);
        }
    };

    const int NKT = DIM / 64;   // 12
    STAGE(0, 0);
    asm volatile("s_waitcnt vmcnt(0)" ::: "memory");
    __builtin_amdgcn_s_barrier();

    for (int t = 0; t < NKT; ++t) {
        const int cur = t & 1;
        if (t + 1 < NKT) STAGE((t + 1) * 64, cur ^ 1);

        #pragma unroll
        for (int ks = 0; ks < 2; ++ks) {
            short8 af[4], bf[2];
            #pragma unroll
            for (int i = 0; i < 4; ++i) {
                const int ra = wr * 64 + i * 16 + col;
                af[i] = *reinterpret_cast<const short8*>(
                    &As[cur][ra][(((ks * 4 + g) ^ (ra & 7)) << 3)]);
            }
            #pragma unroll
            for (int j = 0; j < 2; ++j) {
                const int rb = wc * 32 + j * 16 + col;
                bf[j] = *reinterpret_cast<const short8*>(
                    &Bs[cur][rb][(((ks * 4 + g) ^ (rb & 7)) << 3)]);
            }
            #pragma unroll
            for (int i = 0; i < 4; ++i)
                #pragma unroll
                for (int j = 0; j < 2; ++j)
                    acc[i][j] = __builtin_amdgcn_mfma_f32_16x16x32_bf16(
                        af[i], bf[j], acc[i][j], 0, 0, 0);
        }

        if (t + 1 < NKT) {
            asm volatile("s_waitcnt vmcnt(0)" ::: "memory");
            __builtin_amdgcn_s_barrier();
        }
    }

    #pragma unroll
    for (int j = 0; j < 2; ++j) {
        const int n = n0 + wc * 32 + j * 16 + col;
        const float bj = bias[n];
        #pragma unroll
        for (int i = 0; i < 4; ++i) {
            const int m = m0 + wr * 64 + i * 16 + g * 4;
            #pragma unroll
            for (int r = 0; r < 4; ++r)
                out[(size_t)(m + r) * DIM + n] = acc[i][j][r] + bj;
        }
    }
}

// ---------------------------------------------------------------------------
// Workspace (ushort elems): qb/kb/vt/xb/ctxb 6291456 each; wqT 1769472; woT 589824
// total 33,816,576 ushorts = 67.6 MB
// ---------------------------------------------------------------------------
extern "C" void kernel_launch(void* const* d_in, const int* in_sizes, int n_in,
                              void* d_out, int out_size, void* d_ws, size_t ws_size,
                              hipStream_t stream)
{
    const float* x     = (const float*)d_in[0];
    const float* w_qkv = (const float*)d_in[1];
    const float* b_qkv = (const float*)d_in[2];
    const float* w_out = (const float*)d_in[3];
    const float* b_out = (const float*)d_in[4];
    float* out = (float*)d_out;

    const size_t QSZ = (size_t)NB * HEADS * SEQ * HD;  // 6,291,456
    unsigned short* qb   = (unsigned short*)d_ws;
    unsigned short* kb   = qb + QSZ;
    unsigned short* vt   = kb + QSZ;
    unsigned short* xb   = vt + QSZ;
    unsigned short* ctxb = xb + QSZ;
    unsigned short* wqT  = ctxb + QSZ;
    unsigned short* woT  = wqT + (size_t)NQKV * DIM;

    prep_kernel<<<3648, 256, 0, stream>>>(x, xb, w_qkv, wqT, w_out, woT);
    qkv_gemm_bf16<<<dim3(NQKV / 128, (NB * SEQ) / 128), 512, 0, stream>>>(
        xb, wqT, b_qkv, qb, kb, vt);
    attn_kernel<<<dim3((SEQ / 128) * NB * HEADS), 512, 0, stream>>>(qb, kb, vt, ctxb);
    out_gemm_bf16<<<dim3(DIM / 128, (NB * SEQ) / 128), 512, 0, stream>>>(
        ctxb, woT, b_out, out);
}